// Round 2
// baseline (1914.182 us; speedup 1.0000x reference)
//
#include <hip/hip_runtime.h>
#include <hip/hip_bf16.h>

typedef unsigned short u16;
typedef unsigned int   u32;
using bf16x8 = __attribute__((ext_vector_type(8))) short;
using f32x4  = __attribute__((ext_vector_type(4))) float;

#define T_N    2048
#define NQKV   6144
#define ATTN_SCALE 0.08838834764831845f   // 1/sqrt(128)

// ---------- helpers ----------
__device__ __forceinline__ u16 f2bf(float f) {
  union { float f; u32 u; } v; v.f = f;
  u32 r = v.u + 0x7fffu + ((v.u >> 16) & 1u);
  return (u16)(r >> 16);
}

__device__ __forceinline__ void gl_lds16(const void* g, void* l) {
  __builtin_amdgcn_global_load_lds(
      (const __attribute__((address_space(1))) u32*)g,
      (__attribute__((address_space(3))) u32*)l, 16, 0, 0);
}

// ---------- f32 -> bf16 elementwise (8 elems/thread) ----------
__global__ void cvt_f32_bf16(const float* __restrict__ in, u16* __restrict__ out, int n8) {
  int i = blockIdx.x * blockDim.x + threadIdx.x;
  if (i >= n8) return;
  const float4* p = (const float4*)in + (size_t)i * 2;
  float4 a = p[0], b = p[1];
  union { u16 s[8]; uint4 v; } u;
  u.s[0] = f2bf(a.x); u.s[1] = f2bf(a.y); u.s[2] = f2bf(a.z); u.s[3] = f2bf(a.w);
  u.s[4] = f2bf(b.x); u.s[5] = f2bf(b.y); u.s[6] = f2bf(b.z); u.s[7] = f2bf(b.w);
  ((uint4*)out)[i] = u.v;
}

// ---------- f32 [R][C] -> bf16 [C][R] transpose-convert (out row stride = R) ----------
__global__ void transpose_cvt(const float* __restrict__ in, u16* __restrict__ out,
                              int R, int C) {
  __shared__ float tile[32][33];
  const int r0 = blockIdx.x * 32, c0 = blockIdx.y * 32;
  const int tx = threadIdx.x, ty = threadIdx.y;   // 32 x 8
#pragma unroll
  for (int i = 0; i < 4; ++i)
    tile[ty + 8 * i][tx] = in[(size_t)(r0 + ty + 8 * i) * C + c0 + tx];
  __syncthreads();
#pragma unroll
  for (int i = 0; i < 4; ++i)
    out[(size_t)(c0 + ty + 8 * i) * R + r0 + tx] = f2bf(tile[tx][ty + 8 * i]);
}

// ---------- bf16 GEMM: C[M][N] f32 = A[M][K] * BT[N][K]^T  (m97 structure) ----------
__global__ void gemm_bf16(const u16* __restrict__ A, const u16* __restrict__ BT,
                          float* __restrict__ C, int N, int K) {
  // fragment-linear LDS: slots 0..7 = A m-tiles, 8..15 = B n-tiles; [slot][lane][8]
  __shared__ __align__(16) u16 lds[2][16][64][8];
  const int tid  = threadIdx.x;
  const int w    = tid >> 6, lane = tid & 63;
  const int r    = lane & 15, kg = lane >> 4;
  const int bm   = blockIdx.y * 128, bn = blockIdx.x * 128;
  const int wr   = w >> 1, wc = w & 1;

  const u16* srcs[4];
#pragma unroll
  for (int i = 0; i < 4; ++i) {
    const int s = w * 4 + i;
    if (s < 8) srcs[i] = A  + (size_t)(bm + s * 16 + r) * K + kg * 8;
    else       srcs[i] = BT + (size_t)(bn + (s - 8) * 16 + r) * K + kg * 8;
  }

  f32x4 acc[4][4];
#pragma unroll
  for (int i = 0; i < 4; ++i)
#pragma unroll
    for (int j = 0; j < 4; ++j) acc[i][j] = (f32x4){0.f, 0.f, 0.f, 0.f};

  const int nk = K >> 5;
#pragma unroll
  for (int i = 0; i < 4; ++i)
    gl_lds16(srcs[i], &lds[0][w * 4 + i][0][0]);
  __syncthreads();

  for (int kt = 0; kt < nk; ++kt) {
    const int bi = kt & 1;
    if (kt + 1 < nk) {
      const int koff = (kt + 1) * 32;
#pragma unroll
      for (int i = 0; i < 4; ++i)
        gl_lds16(srcs[i] + koff, &lds[bi ^ 1][w * 4 + i][0][0]);
    }
    bf16x8 af[4], bfg[4];
#pragma unroll
    for (int i = 0; i < 4; ++i)
      af[i] = *(const bf16x8*)&lds[bi][wr * 4 + i][lane][0];
#pragma unroll
    for (int j = 0; j < 4; ++j)
      bfg[j] = *(const bf16x8*)&lds[bi][8 + wc * 4 + j][lane][0];
#pragma unroll
    for (int i = 0; i < 4; ++i)
#pragma unroll
      for (int j = 0; j < 4; ++j)
        acc[i][j] = __builtin_amdgcn_mfma_f32_16x16x32_bf16(af[i], bfg[j], acc[i][j], 0, 0, 0);
    __syncthreads();
  }

#pragma unroll
  for (int i = 0; i < 4; ++i) {
    const int row0 = bm + wr * 64 + i * 16 + kg * 4;
#pragma unroll
    for (int j = 0; j < 4; ++j) {
      const int col = bn + wc * 64 + j * 16 + r;
#pragma unroll
      for (int e = 0; e < 4; ++e)
        C[(size_t)(row0 + e) * N + col] = acc[i][j][e];
    }
  }
}

// ---------- RoPE + pack Q/K to per-(b,head) bf16 [T][D]; Q pre-scaled ----------
__global__ void rope_pack(const float* __restrict__ QKV,
                          const float* __restrict__ cosb, const float* __restrict__ sinb,
                          u16* __restrict__ Qb, u16* __restrict__ Kb) {
  const int bt = blockIdx.x;
  const int b = bt >> 11, t = bt & 2047;
  const float* row = QKV + (size_t)bt * NQKV;
  const int d    = threadIdx.x & 127;
  const int half = threadIdx.x >> 7;
  const float c = cosb[t * 128 + d];
  const float s = sinb[t * 128 + d];
#pragma unroll
  for (int pass = 0; pass < 20; ++pass) {
    const int hh = pass * 2 + half;   // 0..31 = Q heads, 32..39 = K heads
    const int col = (hh < 32) ? hh * 128 + d : 4096 + (hh - 32) * 128 + d;
    const float x  = row[col];
    const float xp = (d < 64) ? -row[col + 64] : row[col - 64];
    const float v  = x * c + xp * s;
    if (hh < 32)
      Qb[((size_t)(b * 32 + hh) * 2048 + t) * 128 + d] = f2bf(v * ATTN_SCALE);
    else
      Kb[((size_t)(b * 8 + (hh - 32)) * 2048 + t) * 128 + d] = f2bf(v);
  }
}

// ---------- V: f32 slice of QKV -> bf16 transposed [b][kh][D][T] ----------
__global__ void v_transpose(const float* __restrict__ QKV, u16* __restrict__ Vt) {
  __shared__ float tile[32][33];
  const int bkh = blockIdx.z;                    // 0..15
  const int b = bkh >> 3, kh = bkh & 7;
  const int t0 = blockIdx.x * 32, d0 = blockIdx.y * 32;
  const int tx = threadIdx.x, ty = threadIdx.y;  // 32 x 8
#pragma unroll
  for (int i = 0; i < 4; ++i) {
    const int t = t0 + ty + 8 * i;
    tile[ty + 8 * i][tx] = QKV[(size_t)(b * 2048 + t) * NQKV + 5120 + kh * 128 + d0 + tx];
  }
  __syncthreads();
#pragma unroll
  for (int i = 0; i < 4; ++i) {
    const int d = d0 + ty + 8 * i;
    Vt[((size_t)bkh * 128 + d) * 2048 + t0 + tx] = f2bf(tile[tx][ty + 8 * i]);
  }
}

// ---------- flash attention (causal, GQA 4:1), 64 q-rows/block, 4 waves ----------
__global__ __launch_bounds__(256) void attn_fwd(
    const u16* __restrict__ Qb, const u16* __restrict__ Kb,
    const u16* __restrict__ Vt, u16* __restrict__ Ob) {
  const int qb = blockIdx.x;                 // q tile (64 rows)
  const int bh = blockIdx.y;                 // b*32 + h
  const int b = bh >> 5, h = bh & 31;
  const int bkh = b * 8 + (h >> 2);
  const int w = threadIdx.x >> 6, lane = threadIdx.x & 63;
  const int r = lane & 15, kg = lane >> 4;
  const int q0 = qb * 64 + w * 16;

  const u16* Qp = Qb + ((size_t)bh * 2048 + q0) * 128;
  const u16* Kp = Kb + (size_t)bkh * 2048 * 128;
  const u16* Vp = Vt + (size_t)bkh * 128 * 2048;   // [d][t]

  __shared__ __align__(16) u16 p_lds[4][16][72];   // +8 pad
  u16 (*pl)[72] = p_lds[w];

  bf16x8 qf[4];
#pragma unroll
  for (int ks = 0; ks < 4; ++ks)
    qf[ks] = *(const bf16x8*)(Qp + r * 128 + ks * 32 + kg * 8);

  f32x4 oacc[8];
#pragma unroll
  for (int dt = 0; dt < 8; ++dt) oacc[dt] = (f32x4){0.f, 0.f, 0.f, 0.f};
  float m_run[4] = {-1e30f, -1e30f, -1e30f, -1e30f};
  float l_run[4] = {0.f, 0.f, 0.f, 0.f};

  for (int kt = 0; kt <= qb; ++kt) {
    const int k0 = kt * 64;
    f32x4 s[4];
#pragma unroll
    for (int nt = 0; nt < 4; ++nt) s[nt] = (f32x4){0.f, 0.f, 0.f, 0.f};
#pragma unroll
    for (int nt = 0; nt < 4; ++nt) {
      const u16* kbase = Kp + (size_t)(k0 + nt * 16 + r) * 128 + kg * 8;
#pragma unroll
      for (int ks = 0; ks < 4; ++ks) {
        bf16x8 kf = *(const bf16x8*)(kbase + ks * 32);
        s[nt] = __builtin_amdgcn_mfma_f32_16x16x32_bf16(qf[ks], kf, s[nt], 0, 0, 0);
      }
    }
    if (kt == qb) {   // diagonal tile: causal mask
#pragma unroll
      for (int nt = 0; nt < 4; ++nt) {
        const int kcol = k0 + nt * 16 + r;
#pragma unroll
        for (int e = 0; e < 4; ++e) {
          const int qrow = q0 + kg * 4 + e;
          if (kcol > qrow) s[nt][e] = -1e30f;
        }
      }
    }
    float sf[4];
#pragma unroll
    for (int e = 0; e < 4; ++e) {
      float v = fmaxf(fmaxf(s[0][e], s[1][e]), fmaxf(s[2][e], s[3][e]));
      v = fmaxf(v, __shfl_xor(v, 1));
      v = fmaxf(v, __shfl_xor(v, 2));
      v = fmaxf(v, __shfl_xor(v, 4));
      v = fmaxf(v, __shfl_xor(v, 8));
      const float mn = fmaxf(m_run[e], v);
      sf[e] = __expf(m_run[e] - mn);
      m_run[e] = mn;
    }
    float rs[4] = {0.f, 0.f, 0.f, 0.f};
#pragma unroll
    for (int nt = 0; nt < 4; ++nt)
#pragma unroll
      for (int e = 0; e < 4; ++e) {
        const float p = __expf(s[nt][e] - m_run[e]);
        s[nt][e] = p;
        rs[e] += p;
      }
#pragma unroll
    for (int e = 0; e < 4; ++e) {
      float v = rs[e];
      v += __shfl_xor(v, 1); v += __shfl_xor(v, 2);
      v += __shfl_xor(v, 4); v += __shfl_xor(v, 8);
      l_run[e] = l_run[e] * sf[e] + v;
    }
#pragma unroll
    for (int dt = 0; dt < 8; ++dt)
#pragma unroll
      for (int e = 0; e < 4; ++e) oacc[dt][e] *= sf[e];
    // P (C-layout) -> LDS -> A-fragment layout
#pragma unroll
    for (int nt = 0; nt < 4; ++nt)
#pragma unroll
      for (int e = 0; e < 4; ++e)
        pl[kg * 4 + e][nt * 16 + r] = f2bf(s[nt][e]);
    asm volatile("" ::: "memory");   // order P writes before reads (DS is in-order per wave)
#pragma unroll
    for (int kstep = 0; kstep < 2; ++kstep) {
      bf16x8 pf = *(const bf16x8*)&pl[r][kstep * 32 + kg * 8];
#pragma unroll
      for (int dt = 0; dt < 8; ++dt) {
        bf16x8 vf = *(const bf16x8*)(Vp + (size_t)(dt * 16 + r) * 2048 + k0 + kstep * 32 + kg * 8);
        oacc[dt] = __builtin_amdgcn_mfma_f32_16x16x32_bf16(pf, vf, oacc[dt], 0, 0, 0);
      }
    }
    asm volatile("" ::: "memory");   // keep next-iter P writes after these reads
  }

  float inv[4];
#pragma unroll
  for (int e = 0; e < 4; ++e) inv[e] = 1.0f / l_run[e];
  const size_t orow0 = (size_t)(b * 2048 + q0 + kg * 4);
#pragma unroll
  for (int dt = 0; dt < 8; ++dt)
#pragma unroll
    for (int e = 0; e < 4; ++e)
      Ob[(orow0 + e) * 4096 + h * 128 + dt * 16 + r] = f2bf(oacc[dt][e] * inv[e]);
}

// ---------- launch ----------
extern "C" void kernel_launch(void* const* d_in, const int* in_sizes, int n_in,
                              void* d_out, int out_size, void* d_ws, size_t ws_size,
                              hipStream_t stream) {
  const float* stm  = (const float*)d_in[0];
  const float* wq   = (const float*)d_in[1];
  const float* wk   = (const float*)d_in[2];
  const float* wv   = (const float*)d_in[3];
  const float* wo   = (const float*)d_in[4];
  const float* cosb = (const float*)d_in[5];
  const float* sinb = (const float*)d_in[6];
  float* out = (float*)d_out;

  char* ws = (char*)d_ws;
  // workspace map (256 MB total)
  u16*   Xb    = (u16*)(ws + 0);           // bf16 [4096][4096]; later reused as attn out Ob
  u16*   WcatT = (u16*)(ws + 33554432);    // bf16 [6144][4096]  (wq|wk|wv transposed)
  u16*   WoT   = (u16*)(ws + 83886080);    // bf16 [4096][4096]
  float* QKV   = (float*)(ws + 117440512); // f32  [4096][6144]
  u16*   Qb    = (u16*)(ws + 218103808);   // bf16 [2][32][2048][128]
  u16*   Kb    = (u16*)(ws + 251658240);   // bf16 [2][8][2048][128]
  u16*   Vt    = (u16*)(ws + 260046848);   // bf16 [2][8][128][2048]

  cvt_f32_bf16<<<8192, 256, 0, stream>>>(stm, Xb, 2097152);
  transpose_cvt<<<dim3(128, 128), dim3(32, 8), 0, stream>>>(wq, WcatT, 4096, 4096);
  transpose_cvt<<<dim3(128, 32),  dim3(32, 8), 0, stream>>>(wk, WcatT + (size_t)4096 * 4096, 4096, 1024);
  transpose_cvt<<<dim3(128, 32),  dim3(32, 8), 0, stream>>>(wv, WcatT + (size_t)5120 * 4096, 4096, 1024);
  transpose_cvt<<<dim3(128, 128), dim3(32, 8), 0, stream>>>(wo, WoT, 4096, 4096);

  gemm_bf16<<<dim3(48, 32), 256, 0, stream>>>(Xb, WcatT, QKV, NQKV, 4096);

  rope_pack<<<4096, 256, 0, stream>>>(QKV, cosb, sinb, Qb, Kb);
  v_transpose<<<dim3(64, 4, 16), dim3(32, 8), 0, stream>>>(QKV, Vt);

  attn_fwd<<<dim3(32, 64), 256, 0, stream>>>(Qb, Kb, Vt, Xb /*Ob*/);

  gemm_bf16<<<dim3(32, 32), 256, 0, stream>>>(Xb, WoT, out, 4096, 4096);
}

// Round 4
// 1069.129 us; speedup vs baseline: 1.7904x; 1.7904x over previous
//
#include <hip/hip_runtime.h>
#include <hip/hip_bf16.h>

typedef unsigned short u16;
typedef unsigned int   u32;
using bf16x8 = __attribute__((ext_vector_type(8))) short;
using f32x4  = __attribute__((ext_vector_type(4))) float;

#define T_N    2048
#define NQKV   6144
#define ATTN_SCALE 0.08838834764831845f   // 1/sqrt(128)

// ---------- helpers ----------
__device__ __forceinline__ u16 f2bf(float f) {
  union { float f; u32 u; } v; v.f = f;
  u32 r = v.u + 0x7fffu + ((v.u >> 16) & 1u);
  return (u16)(r >> 16);
}

__device__ __forceinline__ void gl_lds16(const void* g, void* l) {
  __builtin_amdgcn_global_load_lds(
      (const __attribute__((address_space(1))) u32*)g,
      (__attribute__((address_space(3))) u32*)l, 16, 0, 0);
}

// ---------- f32 -> bf16 elementwise (8 elems/thread) ----------
__global__ void cvt_f32_bf16(const float* __restrict__ in, u16* __restrict__ out, int n8) {
  int i = blockIdx.x * blockDim.x + threadIdx.x;
  if (i >= n8) return;
  const float4* p = (const float4*)in + (size_t)i * 2;
  float4 a = p[0], b = p[1];
  union { u16 s[8]; uint4 v; } u;
  u.s[0] = f2bf(a.x); u.s[1] = f2bf(a.y); u.s[2] = f2bf(a.z); u.s[3] = f2bf(a.w);
  u.s[4] = f2bf(b.x); u.s[5] = f2bf(b.y); u.s[6] = f2bf(b.z); u.s[7] = f2bf(b.w);
  ((uint4*)out)[i] = u.v;
}

// ---------- f32 [R][C] -> bf16 [C][R] transpose-convert (out row stride = R) ----------
__global__ void transpose_cvt(const float* __restrict__ in, u16* __restrict__ out,
                              int R, int C) {
  __shared__ float tile[32][33];
  const int r0 = blockIdx.x * 32, c0 = blockIdx.y * 32;
  const int tx = threadIdx.x, ty = threadIdx.y;   // 32 x 8
#pragma unroll
  for (int i = 0; i < 4; ++i)
    tile[ty + 8 * i][tx] = in[(size_t)(r0 + ty + 8 * i) * C + c0 + tx];
  __syncthreads();
#pragma unroll
  for (int i = 0; i < 4; ++i)
    out[(size_t)(c0 + ty + 8 * i) * R + r0 + tx] = f2bf(tile[tx][ty + 8 * i]);
}

// ---------- bf16 GEMM: C[M][N] f32 = A[M][K] * BT[N][K]^T  (m97 structure) ----------
__global__ void gemm_bf16(const u16* __restrict__ A, const u16* __restrict__ BT,
                          float* __restrict__ C, int N, int K) {
  __shared__ __align__(16) u16 lds[2][16][64][8];
  const int tid  = threadIdx.x;
  const int w    = tid >> 6, lane = tid & 63;
  const int r    = lane & 15, kg = lane >> 4;
  const int bm   = blockIdx.y * 128, bn = blockIdx.x * 128;
  const int wr   = w >> 1, wc = w & 1;

  const u16* srcs[4];
#pragma unroll
  for (int i = 0; i < 4; ++i) {
    const int s = w * 4 + i;
    if (s < 8) srcs[i] = A  + (size_t)(bm + s * 16 + r) * K + kg * 8;
    else       srcs[i] = BT + (size_t)(bn + (s - 8) * 16 + r) * K + kg * 8;
  }

  f32x4 acc[4][4];
#pragma unroll
  for (int i = 0; i < 4; ++i)
#pragma unroll
    for (int j = 0; j < 4; ++j) acc[i][j] = (f32x4){0.f, 0.f, 0.f, 0.f};

  const int nk = K >> 5;
#pragma unroll
  for (int i = 0; i < 4; ++i)
    gl_lds16(srcs[i], &lds[0][w * 4 + i][0][0]);
  __syncthreads();

  for (int kt = 0; kt < nk; ++kt) {
    const int bi = kt & 1;
    if (kt + 1 < nk) {
      const int koff = (kt + 1) * 32;
#pragma unroll
      for (int i = 0; i < 4; ++i)
        gl_lds16(srcs[i] + koff, &lds[bi ^ 1][w * 4 + i][0][0]);
    }
    bf16x8 af[4], bfg[4];
#pragma unroll
    for (int i = 0; i < 4; ++i)
      af[i] = *(const bf16x8*)&lds[bi][wr * 4 + i][lane][0];
#pragma unroll
    for (int j = 0; j < 4; ++j)
      bfg[j] = *(const bf16x8*)&lds[bi][8 + wc * 4 + j][lane][0];
#pragma unroll
    for (int i = 0; i < 4; ++i)
#pragma unroll
      for (int j = 0; j < 4; ++j)
        acc[i][j] = __builtin_amdgcn_mfma_f32_16x16x32_bf16(af[i], bfg[j], acc[i][j], 0, 0, 0);
    __syncthreads();
  }

#pragma unroll
  for (int i = 0; i < 4; ++i) {
    const int row0 = bm + wr * 64 + i * 16 + kg * 4;
#pragma unroll
    for (int j = 0; j < 4; ++j) {
      const int col = bn + wc * 64 + j * 16 + r;
#pragma unroll
      for (int e = 0; e < 4; ++e)
        C[(size_t)(row0 + e) * N + col] = acc[i][j][e];
    }
  }
}

// ---------- RoPE + pack Q/K to per-(b,head) bf16 [T][D]; Q pre-scaled ----------
__global__ void rope_pack(const float* __restrict__ QKV,
                          const float* __restrict__ cosb, const float* __restrict__ sinb,
                          u16* __restrict__ Qb, u16* __restrict__ Kb) {
  const int bt = blockIdx.x;
  const int b = bt >> 11, t = bt & 2047;
  const float* row = QKV + (size_t)bt * NQKV;
  const int d    = threadIdx.x & 127;
  const int half = threadIdx.x >> 7;
  const float c = cosb[t * 128 + d];
  const float s = sinb[t * 128 + d];
#pragma unroll
  for (int pass = 0; pass < 20; ++pass) {
    const int hh = pass * 2 + half;   // 0..31 = Q heads, 32..39 = K heads
    const int col = (hh < 32) ? hh * 128 + d : 4096 + (hh - 32) * 128 + d;
    const float x  = row[col];
    const float xp = (d < 64) ? -row[col + 64] : row[col - 64];
    const float v  = x * c + xp * s;
    if (hh < 32)
      Qb[((size_t)(b * 32 + hh) * 2048 + t) * 128 + d] = f2bf(v * ATTN_SCALE);
    else
      Kb[((size_t)(b * 8 + (hh - 32)) * 2048 + t) * 128 + d] = f2bf(v);
  }
}

// ---------- V: f32 slice of QKV -> bf16 transposed [b][kh][D][T] ----------
__global__ void v_transpose(const float* __restrict__ QKV, u16* __restrict__ Vt) {
  __shared__ float tile[32][33];
  const int bkh = blockIdx.z;                    // 0..15
  const int b = bkh >> 3, kh = bkh & 7;
  const int t0 = blockIdx.x * 32, d0 = blockIdx.y * 32;
  const int tx = threadIdx.x, ty = threadIdx.y;  // 32 x 8
#pragma unroll
  for (int i = 0; i < 4; ++i) {
    const int t = t0 + ty + 8 * i;
    tile[ty + 8 * i][tx] = QKV[(size_t)(b * 2048 + t) * NQKV + 5120 + kh * 128 + d0 + tx];
  }
  __syncthreads();
#pragma unroll
  for (int i = 0; i < 4; ++i) {
    const int d = d0 + ty + 8 * i;
    Vt[((size_t)bkh * 128 + d) * 2048 + t0 + tx] = f2bf(tile[tx][ty + 8 * i]);
  }
}

// ---------- flash attention (causal, GQA 4:1) ----------
// 8 waves x 512 threads; 128 q-rows per phase; paired q-tiles (i, 15-i) for
// perfect balance (34 k-tiles per block); K double-buffered LDS (prefetch),
// V single-buffered (issued at tile start, consumed after mid-tile barrier);
// both XOR-swizzled (byte ^= (row&7)<<4) via pre-swizzled global source.
__global__ __launch_bounds__(512) void attn_fwd(
    const u16* __restrict__ Qb, const u16* __restrict__ Kb,
    const u16* __restrict__ Vt, u16* __restrict__ Ob) {
  const int pair = blockIdx.x;               // 0..7
  const int bh   = blockIdx.y;               // 0..63
  const int b = bh >> 5, h = bh & 31;
  const int bkh = b * 8 + (h >> 2);
  const int tid = threadIdx.x;
  const int w = tid >> 6, lane = tid & 63;
  const int r = lane & 15, kg = lane >> 4;

  const u16*  Qp0 = Qb + (size_t)bh * 2048 * 128;
  const char* Kp  = (const char*)(Kb + (size_t)bkh * 2048 * 128);
  const char* Vp  = (const char*)(Vt + (size_t)bkh * 128 * 2048);

  __shared__ __align__(16) char k_lds[2][64 * 256];   // [64 k][128 d] bf16, swizzled
  __shared__ __align__(16) char v_lds[128 * 128];     // [128 d][64 k] bf16, swizzled
  __shared__ __align__(16) u16  p_lds[8][16][72];
  u16 (*pl)[72] = p_lds[w];

  const int swz = (r & 7) << 4;   // read-side XOR term (row&7 == r&7 for 16-strided rows)

#pragma unroll 1
  for (int ph = 0; ph < 2; ++ph) {
    const int qt = ph ? 15 - pair : pair;
    const int q0 = qt * 128 + w * 16;
    const int nk = (qt + 1) * 2;

    bf16x8 qf[4];
    {
      const u16* Qp = Qp0 + (size_t)q0 * 128;
#pragma unroll
      for (int ks = 0; ks < 4; ++ks)
        qf[ks] = *(const bf16x8*)(Qp + r * 128 + ks * 32 + kg * 8);
    }

    f32x4 oacc[8];
#pragma unroll
    for (int dt = 0; dt < 8; ++dt) oacc[dt] = (f32x4){0.f, 0.f, 0.f, 0.f};
    float m_run[4] = {-1e30f, -1e30f, -1e30f, -1e30f};
    float l_run[4] = {0.f, 0.f, 0.f, 0.f};

    // prologue: stage K tile 0 into buffer 0 (linear LDS, pre-swizzled source)
#pragma unroll
    for (int i = 0; i < 2; ++i) {
      const int o = tid * 16 + i * 8192;
      const int row = o >> 8, colb = o & 255;
      gl_lds16(Kp + (size_t)row * 256 + (colb ^ ((row & 7) << 4)), k_lds[0] + o);
    }
    __syncthreads();
    int cur = 0;

    for (int kt = 0; kt < nk; ++kt) {
      const int k0 = kt * 64;
      // issue V stage for THIS tile (consumed after the mid-tile barrier)
#pragma unroll
      for (int i = 0; i < 2; ++i) {
        const int o = tid * 16 + i * 8192;
        const int row = o >> 7, colb = o & 127;
        gl_lds16(Vp + (size_t)row * 4096 + (size_t)k0 * 2 + (colb ^ ((row & 7) << 4)),
                 v_lds + o);
      }
      // issue K prefetch for NEXT tile
      if (kt + 1 < nk) {
        const int k0n = (kt + 1) * 64;
#pragma unroll
        for (int i = 0; i < 2; ++i) {
          const int o = tid * 16 + i * 8192;
          const int row = o >> 8, colb = o & 255;
          gl_lds16(Kp + (size_t)(k0n + row) * 256 + (colb ^ ((row & 7) << 4)),
                   k_lds[cur ^ 1] + o);
        }
      }

      // ---- QK^T from k_lds[cur] ----
      f32x4 s[4];
#pragma unroll
      for (int nt = 0; nt < 4; ++nt) s[nt] = (f32x4){0.f, 0.f, 0.f, 0.f};
#pragma unroll
      for (int nt = 0; nt < 4; ++nt) {
        const char* kb = k_lds[cur] + (nt * 16 + r) * 256;
#pragma unroll
        for (int ks = 0; ks < 4; ++ks) {
          bf16x8 kf = *(const bf16x8*)(kb + ((ks * 64 + kg * 16) ^ swz));
          s[nt] = __builtin_amdgcn_mfma_f32_16x16x32_bf16(qf[ks], kf, s[nt], 0, 0, 0);
        }
      }

      // ---- causal mask (covers diagonal and fully-masked waves) ----
      if (k0 + 63 > q0) {
#pragma unroll
        for (int nt = 0; nt < 4; ++nt) {
          const int kcol = k0 + nt * 16 + r;
#pragma unroll
          for (int e = 0; e < 4; ++e)
            if (kcol > q0 + kg * 4 + e) s[nt][e] = -1e30f;
        }
      }

      // ---- online softmax ----
      float sf[4];
#pragma unroll
      for (int e = 0; e < 4; ++e) {
        float v = fmaxf(fmaxf(s[0][e], s[1][e]), fmaxf(s[2][e], s[3][e]));
        v = fmaxf(v, __shfl_xor(v, 1));
        v = fmaxf(v, __shfl_xor(v, 2));
        v = fmaxf(v, __shfl_xor(v, 4));
        v = fmaxf(v, __shfl_xor(v, 8));
        const float mn = fmaxf(m_run[e], v);
        sf[e] = __expf(m_run[e] - mn);
        m_run[e] = mn;
      }
      float rs[4] = {0.f, 0.f, 0.f, 0.f};
#pragma unroll
      for (int nt = 0; nt < 4; ++nt)
#pragma unroll
        for (int e = 0; e < 4; ++e) {
          const float p = __expf(s[nt][e] - m_run[e]);
          s[nt][e] = p;
          rs[e] += p;
        }
#pragma unroll
      for (int e = 0; e < 4; ++e) {
        float v = rs[e];
        v += __shfl_xor(v, 1); v += __shfl_xor(v, 2);
        v += __shfl_xor(v, 4); v += __shfl_xor(v, 8);
        l_run[e] = l_run[e] * sf[e] + v;
      }
#pragma unroll
      for (int dt = 0; dt < 8; ++dt)
#pragma unroll
        for (int e = 0; e < 4; ++e) oacc[dt][e] *= sf[e];

      __syncthreads();   // drains vmcnt: V (this tile) and K (next) have landed

      // ---- P (C-layout) -> per-wave LDS -> A-fragment layout ----
#pragma unroll
      for (int nt = 0; nt < 4; ++nt)
#pragma unroll
        for (int e = 0; e < 4; ++e)
          pl[kg * 4 + e][nt * 16 + r] = f2bf(s[nt][e]);
      asm volatile("" ::: "memory");
      // ---- PV from v_lds ----
#pragma unroll
      for (int kstep = 0; kstep < 2; ++kstep) {
        bf16x8 pf = *(const bf16x8*)&pl[r][kstep * 32 + kg * 8];
#pragma unroll
        for (int dt = 0; dt < 8; ++dt) {
          const char* vb = v_lds + (dt * 16 + r) * 128 + ((kstep * 64 + kg * 16) ^ swz);
          bf16x8 vf = *(const bf16x8*)vb;
          oacc[dt] = __builtin_amdgcn_mfma_f32_16x16x32_bf16(pf, vf, oacc[dt], 0, 0, 0);
        }
      }
      asm volatile("" ::: "memory");
      __syncthreads();   // v_lds / p_lds free for next tile
      cur ^= 1;
    }

    // ---- epilogue: normalize + store ----
    float inv[4];
#pragma unroll
    for (int e = 0; e < 4; ++e) inv[e] = 1.0f / l_run[e];
    const size_t orow0 = (size_t)(b * 2048 + q0 + kg * 4);
#pragma unroll
    for (int dt = 0; dt < 8; ++dt)
#pragma unroll
      for (int e = 0; e < 4; ++e)
        Ob[(orow0 + e) * 4096 + h * 128 + dt * 16 + r] = f2bf(oacc[dt][e] * inv[e]);
    __syncthreads();   // before next phase's prologue staging
  }
}

// ---------- launch ----------
extern "C" void kernel_launch(void* const* d_in, const int* in_sizes, int n_in,
                              void* d_out, int out_size, void* d_ws, size_t ws_size,
                              hipStream_t stream) {
  const float* stm  = (const float*)d_in[0];
  const float* wq   = (const float*)d_in[1];
  const float* wk   = (const float*)d_in[2];
  const float* wv   = (const float*)d_in[3];
  const float* wo   = (const float*)d_in[4];
  const float* cosb = (const float*)d_in[5];
  const float* sinb = (const float*)d_in[6];
  float* out = (float*)d_out;

  char* ws = (char*)d_ws;
  u16*   Xb    = (u16*)(ws + 0);           // bf16 [4096][4096]; reused as attn out Ob
  u16*   WcatT = (u16*)(ws + 33554432);    // bf16 [6144][4096]
  u16*   WoT   = (u16*)(ws + 83886080);    // bf16 [4096][4096]
  float* QKV   = (float*)(ws + 117440512); // f32  [4096][6144]
  u16*   Qb    = (u16*)(ws + 218103808);   // bf16 [2][32][2048][128]
  u16*   Kb    = (u16*)(ws + 251658240);   // bf16 [2][8][2048][128]
  u16*   Vt    = (u16*)(ws + 260046848);   // bf16 [2][8][128][2048]

  cvt_f32_bf16<<<8192, 256, 0, stream>>>(stm, Xb, 2097152);
  transpose_cvt<<<dim3(128, 128), dim3(32, 8), 0, stream>>>(wq, WcatT, 4096, 4096);
  transpose_cvt<<<dim3(128, 32),  dim3(32, 8), 0, stream>>>(wk, WcatT + (size_t)4096 * 4096, 4096, 1024);
  transpose_cvt<<<dim3(128, 32),  dim3(32, 8), 0, stream>>>(wv, WcatT + (size_t)5120 * 4096, 4096, 1024);
  transpose_cvt<<<dim3(128, 128), dim3(32, 8), 0, stream>>>(wo, WoT, 4096, 4096);

  gemm_bf16<<<dim3(48, 32), 256, 0, stream>>>(Xb, WcatT, QKV, NQKV, 4096);

  rope_pack<<<4096, 256, 0, stream>>>(QKV, cosb, sinb, Qb, Kb);
  v_transpose<<<dim3(64, 4, 16), dim3(32, 8), 0, stream>>>(QKV, Vt);

  attn_fwd<<<dim3(8, 64), 512, 0, stream>>>(Qb, Kb, Vt, Xb /*Ob*/);

  gemm_bf16<<<dim3(32, 32), 256, 0, stream>>>(Xb, WoT, out, 4096, 4096);
}

// Round 5
// 872.432 us; speedup vs baseline: 2.1941x; 1.2255x over previous
//
#include <hip/hip_runtime.h>
#include <hip/hip_bf16.h>

typedef unsigned short u16;
typedef unsigned int   u32;
using bf16x8 = __attribute__((ext_vector_type(8))) short;
using f32x4  = __attribute__((ext_vector_type(4))) float;

#define T_N    2048
#define NQKV   6144
#define ATTN_SCALE 0.08838834764831845f   // 1/sqrt(128)

// ---------- helpers ----------
__device__ __forceinline__ u16 f2bf(float f) {
  union { float f; u32 u; } v; v.f = f;
  u32 r = v.u + 0x7fffu + ((v.u >> 16) & 1u);
  return (u16)(r >> 16);
}

__device__ __forceinline__ void gl_lds16(const void* g, void* l) {
  __builtin_amdgcn_global_load_lds(
      (const __attribute__((address_space(1))) u32*)g,
      (__attribute__((address_space(3))) u32*)l, 16, 0, 0);
}

// ---------- f32 -> bf16 elementwise (8 elems/thread) ----------
__global__ void cvt_f32_bf16(const float* __restrict__ in, u16* __restrict__ out, int n8) {
  int i = blockIdx.x * blockDim.x + threadIdx.x;
  if (i >= n8) return;
  const float4* p = (const float4*)in + (size_t)i * 2;
  float4 a = p[0], b = p[1];
  union { u16 s[8]; uint4 v; } u;
  u.s[0] = f2bf(a.x); u.s[1] = f2bf(a.y); u.s[2] = f2bf(a.z); u.s[3] = f2bf(a.w);
  u.s[4] = f2bf(b.x); u.s[5] = f2bf(b.y); u.s[6] = f2bf(b.z); u.s[7] = f2bf(b.w);
  ((uint4*)out)[i] = u.v;
}

// ---------- f32 [R][C] -> bf16 [C][R] transpose-convert ----------
__global__ void transpose_cvt(const float* __restrict__ in, u16* __restrict__ out,
                              int R, int C) {
  __shared__ float tile[32][33];
  const int r0 = blockIdx.x * 32, c0 = blockIdx.y * 32;
  const int tx = threadIdx.x, ty = threadIdx.y;   // 32 x 8
#pragma unroll
  for (int i = 0; i < 4; ++i)
    tile[ty + 8 * i][tx] = in[(size_t)(r0 + ty + 8 * i) * C + c0 + tx];
  __syncthreads();
#pragma unroll
  for (int i = 0; i < 4; ++i)
    out[(size_t)(c0 + ty + 8 * i) * R + r0 + tx] = f2bf(tile[tx][ty + 8 * i]);
}

// ---------- bf16 GEMM, 256x256 tile, BK=64, 8 waves (2Mx4N) ----------
// C[M][N] f32 = A[M][K] * BT[N][K]^T.  T1 XCD swizzle (grid%8==0 required),
// T2 LDS XOR-swizzle (pre-swizzled global source + swizzled ds_read),
// T5 setprio around MFMA quadrant clusters, full-tile prefetch per K-step.
__global__ __launch_bounds__(512, 2) void gemm256_bf16(
    const u16* __restrict__ A, const u16* __restrict__ BT,
    float* __restrict__ C, int N, int K, int nbx) {
  __shared__ __align__(16) char lA[2][32768];   // [256 rows][64 k] bf16, swizzled
  __shared__ __align__(16) char lB[2][32768];
  const int tid = threadIdx.x;
  const int w = tid >> 6, lane = tid & 63;
  const int r = lane & 15, kg = lane >> 4;
  const int wm = w >> 2, wn = w & 3;

  // T1: bijective XCD swizzle (gridDim.x % 8 == 0)
  int bid = blockIdx.x;
  const int cpx = gridDim.x >> 3;
  bid = (bid & 7) * cpx + (bid >> 3);
  const int bx = bid % nbx, by = bid / nbx;

  const size_t Kb = (size_t)K * 2;
  const char* Ab = (const char*)A  + (size_t)(by << 8) * Kb;
  const char* Bb = (const char*)BT + (size_t)(bx << 8) * Kb;

  // staging map: thread -> two 16B chunks of a 128x128B half-tile
  const int o1 = tid * 16, o2 = o1 + 8192;
  const int sr1 = o1 >> 7, sc1 = (o1 & 127) ^ ((sr1 & 7) << 4);
  const int sr2 = o2 >> 7, sc2 = (o2 & 127) ^ ((sr2 & 7) << 4);

#define STAGE256(buf, ktb)                                                       \
  do {                                                                           \
    gl_lds16(Ab + (size_t)sr1 * Kb + (ktb) + sc1, &lA[buf][o1]);                 \
    gl_lds16(Ab + (size_t)sr2 * Kb + (ktb) + sc2, &lA[buf][o2]);                 \
    gl_lds16(Ab + (size_t)(128 + sr1) * Kb + (ktb) + sc1, &lA[buf][16384 + o1]); \
    gl_lds16(Ab + (size_t)(128 + sr2) * Kb + (ktb) + sc2, &lA[buf][16384 + o2]); \
    gl_lds16(Bb + (size_t)sr1 * Kb + (ktb) + sc1, &lB[buf][o1]);                 \
    gl_lds16(Bb + (size_t)sr2 * Kb + (ktb) + sc2, &lB[buf][o2]);                 \
    gl_lds16(Bb + (size_t)(128 + sr1) * Kb + (ktb) + sc1, &lB[buf][16384 + o1]); \
    gl_lds16(Bb + (size_t)(128 + sr2) * Kb + (ktb) + sc2, &lB[buf][16384 + o2]); \
  } while (0)

  f32x4 acc[8][4];
#pragma unroll
  for (int i = 0; i < 8; ++i)
#pragma unroll
    for (int j = 0; j < 4; ++j) acc[i][j] = (f32x4){0.f, 0.f, 0.f, 0.f};

  const int nk = K >> 6;
  STAGE256(0, 0);
  __syncthreads();

  const int swz = (r & 7) << 4;
#pragma unroll 2
  for (int kt = 0; kt < nk; ++kt) {
    const int cur = kt & 1;
    if (kt + 1 < nk) STAGE256(cur ^ 1, (size_t)(kt + 1) << 7);
    const char* pa = lA[cur] + wm * 16384 + r * 128;
    const char* pb = lB[cur] + wn * 8192 + r * 128;
    bf16x8 bfr[4][2];
#pragma unroll
    for (int ni = 0; ni < 4; ++ni)
#pragma unroll
      for (int ks = 0; ks < 2; ++ks)
        bfr[ni][ks] = *(const bf16x8*)(pb + ni * 2048 + ((ks * 64 + kg * 16) ^ swz));
#pragma unroll
    for (int p = 0; p < 4; ++p) {
      bf16x8 af[2][2];
#pragma unroll
      for (int m2 = 0; m2 < 2; ++m2)
#pragma unroll
        for (int ks = 0; ks < 2; ++ks)
          af[m2][ks] = *(const bf16x8*)(pa + (p * 2 + m2) * 2048 + ((ks * 64 + kg * 16) ^ swz));
      __builtin_amdgcn_s_setprio(1);
#pragma unroll
      for (int m2 = 0; m2 < 2; ++m2)
#pragma unroll
        for (int ni = 0; ni < 4; ++ni)
#pragma unroll
          for (int ks = 0; ks < 2; ++ks)
            acc[p * 2 + m2][ni] = __builtin_amdgcn_mfma_f32_16x16x32_bf16(
                af[m2][ks], bfr[ni][ks], acc[p * 2 + m2][ni], 0, 0, 0);
      __builtin_amdgcn_s_setprio(0);
    }
    __syncthreads();
  }
#undef STAGE256

  float* Cp = C + (size_t)((by << 8) + wm * 128 + kg * 4) * N + (bx << 8) + wn * 64 + r;
#pragma unroll
  for (int mi = 0; mi < 8; ++mi)
#pragma unroll
    for (int e = 0; e < 4; ++e) {
      float* rowp = Cp + (size_t)(mi * 16 + e) * N;
#pragma unroll
      for (int ni = 0; ni < 4; ++ni)
        rowp[ni * 16] = acc[mi][ni][e];
    }
}

// ---------- RoPE + pack Q/K to per-(b,head) bf16 [T][D]; Q pre-scaled ----------
__global__ void rope_pack(const float* __restrict__ QKV,
                          const float* __restrict__ cosb, const float* __restrict__ sinb,
                          u16* __restrict__ Qb, u16* __restrict__ Kb) {
  const int bt = blockIdx.x;
  const int b = bt >> 11, t = bt & 2047;
  const float* row = QKV + (size_t)bt * NQKV;
  const int d    = threadIdx.x & 127;
  const int half = threadIdx.x >> 7;
  const float c = cosb[t * 128 + d];
  const float s = sinb[t * 128 + d];
#pragma unroll
  for (int pass = 0; pass < 20; ++pass) {
    const int hh = pass * 2 + half;   // 0..31 = Q heads, 32..39 = K heads
    const int col = (hh < 32) ? hh * 128 + d : 4096 + (hh - 32) * 128 + d;
    const float x  = row[col];
    const float xp = (d < 64) ? -row[col + 64] : row[col - 64];
    const float v  = x * c + xp * s;
    if (hh < 32)
      Qb[((size_t)(b * 32 + hh) * 2048 + t) * 128 + d] = f2bf(v * ATTN_SCALE);
    else
      Kb[((size_t)(b * 8 + (hh - 32)) * 2048 + t) * 128 + d] = f2bf(v);
  }
}

// ---------- V: f32 slice of QKV -> bf16 transposed [b][kh][D][T] ----------
__global__ void v_transpose(const float* __restrict__ QKV, u16* __restrict__ Vt) {
  __shared__ float tile[32][33];
  const int bkh = blockIdx.z;                    // 0..15
  const int b = bkh >> 3, kh = bkh & 7;
  const int t0 = blockIdx.x * 32, d0 = blockIdx.y * 32;
  const int tx = threadIdx.x, ty = threadIdx.y;  // 32 x 8
#pragma unroll
  for (int i = 0; i < 4; ++i) {
    const int t = t0 + ty + 8 * i;
    tile[ty + 8 * i][tx] = QKV[(size_t)(b * 2048 + t) * NQKV + 5120 + kh * 128 + d0 + tx];
  }
  __syncthreads();
#pragma unroll
  for (int i = 0; i < 4; ++i) {
    const int d = d0 + ty + 8 * i;
    Vt[((size_t)bkh * 128 + d) * 2048 + t0 + tx] = f2bf(tile[tx][ty + 8 * i]);
  }
}

// ---------- flash attention (causal, GQA 4:1) ----------
__global__ __launch_bounds__(512) void attn_fwd(
    const u16* __restrict__ Qb, const u16* __restrict__ Kb,
    const u16* __restrict__ Vt, u16* __restrict__ Ob) {
  const int pair = blockIdx.x;               // 0..7
  const int bh   = blockIdx.y;               // 0..63
  const int b = bh >> 5, h = bh & 31;
  const int bkh = b * 8 + (h >> 2);
  const int tid = threadIdx.x;
  const int w = tid >> 6, lane = tid & 63;
  const int r = lane & 15, kg = lane >> 4;

  const u16*  Qp0 = Qb + (size_t)bh * 2048 * 128;
  const char* Kp  = (const char*)(Kb + (size_t)bkh * 2048 * 128);
  const char* Vp  = (const char*)(Vt + (size_t)bkh * 128 * 2048);

  __shared__ __align__(16) char k_lds[2][64 * 256];   // [64 k][128 d] bf16, swizzled
  __shared__ __align__(16) char v_lds[128 * 128];     // [128 d][64 k] bf16, swizzled
  __shared__ __align__(16) u16  p_lds[8][16][72];
  u16 (*pl)[72] = p_lds[w];

  const int swz = (r & 7) << 4;

#pragma unroll 1
  for (int ph = 0; ph < 2; ++ph) {
    const int qt = ph ? 15 - pair : pair;
    const int q0 = qt * 128 + w * 16;
    const int nk = (qt + 1) * 2;

    bf16x8 qf[4];
    {
      const u16* Qp = Qp0 + (size_t)q0 * 128;
#pragma unroll
      for (int ks = 0; ks < 4; ++ks)
        qf[ks] = *(const bf16x8*)(Qp + r * 128 + ks * 32 + kg * 8);
    }

    f32x4 oacc[8];
#pragma unroll
    for (int dt = 0; dt < 8; ++dt) oacc[dt] = (f32x4){0.f, 0.f, 0.f, 0.f};
    float m_run[4] = {-1e30f, -1e30f, -1e30f, -1e30f};
    float l_run[4] = {0.f, 0.f, 0.f, 0.f};

#pragma unroll
    for (int i = 0; i < 2; ++i) {
      const int o = tid * 16 + i * 8192;
      const int row = o >> 8, colb = o & 255;
      gl_lds16(Kp + (size_t)row * 256 + (colb ^ ((row & 7) << 4)), k_lds[0] + o);
    }
    __syncthreads();
    int cur = 0;

    for (int kt = 0; kt < nk; ++kt) {
      const int k0 = kt * 64;
#pragma unroll
      for (int i = 0; i < 2; ++i) {
        const int o = tid * 16 + i * 8192;
        const int row = o >> 7, colb = o & 127;
        gl_lds16(Vp + (size_t)row * 4096 + (size_t)k0 * 2 + (colb ^ ((row & 7) << 4)),
                 v_lds + o);
      }
      if (kt + 1 < nk) {
        const int k0n = (kt + 1) * 64;
#pragma unroll
        for (int i = 0; i < 2; ++i) {
          const int o = tid * 16 + i * 8192;
          const int row = o >> 8, colb = o & 255;
          gl_lds16(Kp + (size_t)(k0n + row) * 256 + (colb ^ ((row & 7) << 4)),
                   k_lds[cur ^ 1] + o);
        }
      }

      f32x4 s[4];
#pragma unroll
      for (int nt = 0; nt < 4; ++nt) s[nt] = (f32x4){0.f, 0.f, 0.f, 0.f};
#pragma unroll
      for (int nt = 0; nt < 4; ++nt) {
        const char* kb = k_lds[cur] + (nt * 16 + r) * 256;
#pragma unroll
        for (int ks = 0; ks < 4; ++ks) {
          bf16x8 kf = *(const bf16x8*)(kb + ((ks * 64 + kg * 16) ^ swz));
          s[nt] = __builtin_amdgcn_mfma_f32_16x16x32_bf16(qf[ks], kf, s[nt], 0, 0, 0);
        }
      }

      if (k0 + 63 > q0) {
#pragma unroll
        for (int nt = 0; nt < 4; ++nt) {
          const int kcol = k0 + nt * 16 + r;
#pragma unroll
          for (int e = 0; e < 4; ++e)
            if (kcol > q0 + kg * 4 + e) s[nt][e] = -1e30f;
        }
      }

      float sf[4];
#pragma unroll
      for (int e = 0; e < 4; ++e) {
        float v = fmaxf(fmaxf(s[0][e], s[1][e]), fmaxf(s[2][e], s[3][e]));
        v = fmaxf(v, __shfl_xor(v, 1));
        v = fmaxf(v, __shfl_xor(v, 2));
        v = fmaxf(v, __shfl_xor(v, 4));
        v = fmaxf(v, __shfl_xor(v, 8));
        const float mn = fmaxf(m_run[e], v);
        sf[e] = __expf(m_run[e] - mn);
        m_run[e] = mn;
      }
      float rs[4] = {0.f, 0.f, 0.f, 0.f};
#pragma unroll
      for (int nt = 0; nt < 4; ++nt)
#pragma unroll
        for (int e = 0; e < 4; ++e) {
          const float p = __expf(s[nt][e] - m_run[e]);
          s[nt][e] = p;
          rs[e] += p;
        }
#pragma unroll
      for (int e = 0; e < 4; ++e) {
        float v = rs[e];
        v += __shfl_xor(v, 1); v += __shfl_xor(v, 2);
        v += __shfl_xor(v, 4); v += __shfl_xor(v, 8);
        l_run[e] = l_run[e] * sf[e] + v;
      }
#pragma unroll
      for (int dt = 0; dt < 8; ++dt)
#pragma unroll
        for (int e = 0; e < 4; ++e) oacc[dt][e] *= sf[e];

      __syncthreads();

#pragma unroll
      for (int nt = 0; nt < 4; ++nt)
#pragma unroll
        for (int e = 0; e < 4; ++e)
          pl[kg * 4 + e][nt * 16 + r] = f2bf(s[nt][e]);
      asm volatile("" ::: "memory");
#pragma unroll
      for (int kstep = 0; kstep < 2; ++kstep) {
        bf16x8 pf = *(const bf16x8*)&pl[r][kstep * 32 + kg * 8];
#pragma unroll
        for (int dt = 0; dt < 8; ++dt) {
          const char* vb = v_lds + (dt * 16 + r) * 128 + ((kstep * 64 + kg * 16) ^ swz);
          bf16x8 vf = *(const bf16x8*)vb;
          oacc[dt] = __builtin_amdgcn_mfma_f32_16x16x32_bf16(pf, vf, oacc[dt], 0, 0, 0);
        }
      }
      asm volatile("" ::: "memory");
      __syncthreads();
      cur ^= 1;
    }

    float inv[4];
#pragma unroll
    for (int e = 0; e < 4; ++e) inv[e] = 1.0f / l_run[e];
    const size_t orow0 = (size_t)(b * 2048 + q0 + kg * 4);
#pragma unroll
    for (int dt = 0; dt < 8; ++dt)
#pragma unroll
      for (int e = 0; e < 4; ++e)
        Ob[(orow0 + e) * 4096 + h * 128 + dt * 16 + r] = f2bf(oacc[dt][e] * inv[e]);
    __syncthreads();
  }
}

// ---------- launch ----------
extern "C" void kernel_launch(void* const* d_in, const int* in_sizes, int n_in,
                              void* d_out, int out_size, void* d_ws, size_t ws_size,
                              hipStream_t stream) {
  const float* stm  = (const float*)d_in[0];
  const float* wq   = (const float*)d_in[1];
  const float* wk   = (const float*)d_in[2];
  const float* wv   = (const float*)d_in[3];
  const float* wo   = (const float*)d_in[4];
  const float* cosb = (const float*)d_in[5];
  const float* sinb = (const float*)d_in[6];
  float* out = (float*)d_out;

  char* ws = (char*)d_ws;
  u16*   Xb    = (u16*)(ws + 0);           // bf16 [4096][4096]; reused as attn out Ob
  u16*   WcatT = (u16*)(ws + 33554432);    // bf16 [6144][4096]
  u16*   WoT   = (u16*)(ws + 83886080);    // bf16 [4096][4096]
  float* QKV   = (float*)(ws + 117440512); // f32  [4096][6144]
  u16*   Qb    = (u16*)(ws + 218103808);   // bf16 [2][32][2048][128]
  u16*   Kb    = (u16*)(ws + 251658240);   // bf16 [2][8][2048][128]
  u16*   Vt    = (u16*)(ws + 260046848);   // bf16 [2][8][128][2048]

  cvt_f32_bf16<<<8192, 256, 0, stream>>>(stm, Xb, 2097152);
  transpose_cvt<<<dim3(128, 128), dim3(32, 8), 0, stream>>>(wq, WcatT, 4096, 4096);
  transpose_cvt<<<dim3(128, 32),  dim3(32, 8), 0, stream>>>(wk, WcatT + (size_t)4096 * 4096, 4096, 1024);
  transpose_cvt<<<dim3(128, 32),  dim3(32, 8), 0, stream>>>(wv, WcatT + (size_t)5120 * 4096, 4096, 1024);
  transpose_cvt<<<dim3(128, 128), dim3(32, 8), 0, stream>>>(wo, WoT, 4096, 4096);

  // QKV GEMM: M=4096, N=6144, K=4096 -> grid 24x16 = 384 (%8==0)
  gemm256_bf16<<<384, 512, 0, stream>>>(Xb, WcatT, QKV, NQKV, 4096, 24);

  rope_pack<<<4096, 256, 0, stream>>>(QKV, cosb, sinb, Qb, Kb);
  v_transpose<<<dim3(64, 4, 16), dim3(32, 8), 0, stream>>>(QKV, Vt);

  attn_fwd<<<dim3(8, 64), 512, 0, stream>>>(Qb, Kb, Vt, Xb /*Ob*/);

  // WO GEMM: 4096x4096x4096 -> grid 16x16 = 256 (%8==0)
  gemm256_bf16<<<256, 512, 0, stream>>>(Xb, WoT, out, 4096, 4096, 16);
}